// Round 1
// baseline (212.668 us; speedup 1.0000x reference)
//
#include <hip/hip_runtime.h>
#include <hip/hip_bf16.h>

// SineLayer: y[b,o] = sum_{i,d} sin(w_d*x[b,i]+p_d) * (scale_d*c[o,i,d]) + offs[o]
//   offs[o] = bias[o] + sum_{i,d} mu_d*scale_d*c[o,i,d]   (x-independent)
// GEMM: M=32768 (batch), N=512 (n_out), K=4096 (n_in*D), bf16 MFMA 16x16x32.

#define BATCH 32768
#define NIN   256
#define NOUT  512
#define DDIM  16
#define BM    128
#define BN    128
#define BK    64
#define NKT   ((NIN*DDIM)/BK)     // 64 K-steps
#define TILE_BYTES (BN*BK*2)      // 16 KB per (o_blk, kt) tile
#define EPSV  1e-8f

typedef short  bf16x8 __attribute__((ext_vector_type(8)));
typedef float  f32x4  __attribute__((ext_vector_type(4)));

static __device__ __forceinline__ ushort f2bf(float f) {
  union { __hip_bfloat16 h; ushort u; } cv;
  cv.h = __float2bfloat16(f);
  return cv.u;
}

// ---------------------------------------------------------------------------
// Prep: cb[o,k] = bf16(scale_d * c[o,i,d]) stored as pre-swizzled 128x64 tiles
// (tile index = o_blk*NKT + kt; within tile: byte = (r*128 + kloc*2) ^ ((r&7)<<4))
// so that a LINEAR global_load_lds copy yields the swizzled LDS image.
// Also offs[o] = bias[o] + sum mu_d*scale_d*c[o,i,d].
// ---------------------------------------------------------------------------
__global__ __launch_bounds__(256) void prep_kernel(
    const float* __restrict__ omega, const float* __restrict__ phase,
    const float* __restrict__ c_basis, const float* __restrict__ bias,
    ushort* __restrict__ cb, float* __restrict__ offs)
{
  __shared__ float s_scale[DDIM];
  __shared__ float s_musc[DDIM];
  __shared__ float s_red[4];

  const int o = blockIdx.x;
  const int t = threadIdx.x;

  if (t < DDIM) {
    float w = omega[t];
    float p = phase[t];
    float mu  = expf(-0.5f * w * w) * sinf(p);
    float var = 0.5f * (1.0f - expf(-2.0f * w * w) * cosf(2.0f * p)) - mu * mu;
    float sd  = sqrtf(fmaxf(var, 0.0f));
    float sc  = 1.0f / (sd + EPSV);
    s_scale[t] = sc;
    s_musc[t]  = mu * sc;
  }
  __syncthreads();

  // thread t handles (o, i=t): 16 contiguous floats (64B) -> fully coalesced
  const float* cp = c_basis + ((size_t)o * NIN + t) * DDIM;
  float cv[DDIM];
  {
    const float4* cp4 = (const float4*)cp;
    float4 a = cp4[0], b = cp4[1], c = cp4[2], d = cp4[3];
    cv[0]=a.x; cv[1]=a.y; cv[2]=a.z; cv[3]=a.w;
    cv[4]=b.x; cv[5]=b.y; cv[6]=b.z; cv[7]=b.w;
    cv[8]=c.x; cv[9]=c.y; cv[10]=c.z; cv[11]=c.w;
    cv[12]=d.x; cv[13]=d.y; cv[14]=d.z; cv[15]=d.w;
  }

  float partial = 0.0f;
  uint pk[8];
#pragma unroll
  for (int d = 0; d < DDIM; d += 2) {
    partial += cv[d] * s_musc[d] + cv[d+1] * s_musc[d+1];
    ushort u0 = f2bf(cv[d]   * s_scale[d]);
    ushort u1 = f2bf(cv[d+1] * s_scale[d+1]);
    pk[d >> 1] = (uint)u0 | ((uint)u1 << 16);
  }

  // write position: k = i*16+d ; kt = i/4 ; kloc = (i&3)*16+d ; r = o%128
  {
    const int r     = o & (BM - 1);
    const int o_blk = o >> 7;
    const int kt    = t >> 2;
    const int swz   = (r & 7) << 4;
    char* tile = (char*)cb + (size_t)(o_blk * NKT + kt) * TILE_BYTES;
    int b0 = r * 128 + (t & 3) * 32;
    *(uint4*)(tile + ((b0     ) ^ swz)) = make_uint4(pk[0], pk[1], pk[2], pk[3]);
    *(uint4*)(tile + ((b0 + 16) ^ swz)) = make_uint4(pk[4], pk[5], pk[6], pk[7]);
  }

  // block-reduce partial -> offs[o]
#pragma unroll
  for (int off = 32; off > 0; off >>= 1) partial += __shfl_down(partial, off, 64);
  if ((t & 63) == 0) s_red[t >> 6] = partial;
  __syncthreads();
  if (t == 0) offs[o] = bias[o] + s_red[0] + s_red[1] + s_red[2] + s_red[3];
}

// ---------------------------------------------------------------------------
// Main GEMM: 128x128 tile, BK=64, 4 waves (2x2, each 64x64 = 4x4 frags of 16x16).
// A = sin(w*x+p) computed on the fly -> swizzled LDS; B via global_load_lds
// (linear copy of pre-swizzled tile). XOR swizzle kills the 16-way ds_read conflict.
// ---------------------------------------------------------------------------
__global__ __launch_bounds__(256) void gemm_kernel(
    const float* __restrict__ x, const float* __restrict__ omega,
    const float* __restrict__ phase, const ushort* __restrict__ cb,
    const float* __restrict__ offs, float* __restrict__ out)
{
  __shared__ ushort As[BM * BK];   // 16 KB, swizzled
  __shared__ ushort Bs[BN * BK];   // 16 KB, swizzled

  const int t    = threadIdx.x;
  const int lane = t & 63;
  const int wid  = t >> 6;
  const int wm   = wid >> 1;       // 0..1
  const int wn   = wid & 1;        // 0..1
  const int bm   = blockIdx.x >> 2;
  const int bn   = blockIdx.x & 3; // bn in low bits: 4 col-blocks share x-tile in L2
  const int row0 = bm * BM;
  const int col0 = bn * BN;

  // per-thread copy of omega/phase (16 each; uniform -> cached)
  float wv[DDIM], pv[DDIM];
#pragma unroll
  for (int d = 0; d < DDIM; ++d) { wv[d] = omega[d]; pv[d] = phase[d]; }

  f32x4 acc[4][4];
#pragma unroll
  for (int m = 0; m < 4; ++m)
#pragma unroll
    for (int n = 0; n < 4; ++n) acc[m][n] = (f32x4){0.f, 0.f, 0.f, 0.f};

  // A staging assignment: thread -> (row r = t>>1, x-col pair (t&1)*2)
  const int xr  = t >> 1;
  const int xc2 = (t & 1) * 2;
  const float* xbase = x + (size_t)(row0 + xr) * NIN + xc2;

  char* AsB = (char*)As;
  char* BsB = (char*)Bs;
  const char* cbB = (const char*)cb + (size_t)bn * NKT * TILE_BYTES;

  const int hi  = lane >> 4;       // 0..3
  const int l15 = lane & 15;

  for (int kt = 0; kt < NKT; ++kt) {
    // ---- issue B staging first (async global->LDS, 16 KB linear) ----
    {
      const char* src = cbB + (size_t)kt * TILE_BYTES + wid * 4096 + lane * 16;
      char* dst = BsB + wid * 4096;  // wave-uniform base; HW adds lane*16
      __builtin_amdgcn_global_load_lds(
          (const __attribute__((address_space(1))) void*)(src),
          (__attribute__((address_space(3))) void*)(dst), 16, 0, 0);
      __builtin_amdgcn_global_load_lds(
          (const __attribute__((address_space(1))) void*)(src + 1024),
          (__attribute__((address_space(3))) void*)(dst + 1024), 16, 0, 0);
      __builtin_amdgcn_global_load_lds(
          (const __attribute__((address_space(1))) void*)(src + 2048),
          (__attribute__((address_space(3))) void*)(dst + 2048), 16, 0, 0);
      __builtin_amdgcn_global_load_lds(
          (const __attribute__((address_space(1))) void*)(src + 3072),
          (__attribute__((address_space(3))) void*)(dst + 3072), 16, 0, 0);
    }

    // ---- stage A: 2 x-values -> 32 sins -> bf16 -> swizzled ds_write ----
    {
      float2 xv = *(const float2*)(xbase + kt * 4);
      const int swz = (xr & 7) << 4;
#pragma unroll
      for (int j = 0; j < 2; ++j) {
        float xx = j ? xv.y : xv.x;
        uint pk[8];
#pragma unroll
        for (int d = 0; d < DDIM; d += 2) {
          float s0 = __sinf(fmaf(wv[d],   xx, pv[d]));
          float s1 = __sinf(fmaf(wv[d+1], xx, pv[d+1]));
          pk[d >> 1] = (uint)f2bf(s0) | ((uint)f2bf(s1) << 16);
        }
        int b0 = xr * 128 + (xc2 + j) * 32;
        *(uint4*)(AsB + ((b0     ) ^ swz)) = make_uint4(pk[0], pk[1], pk[2], pk[3]);
        *(uint4*)(AsB + ((b0 + 16) ^ swz)) = make_uint4(pk[4], pk[5], pk[6], pk[7]);
      }
    }

    __syncthreads();  // drains vmcnt (global_load_lds) + lgkm (ds_write)

    // ---- MFMA: 2 k-chunks of 32, 4x4 fragments ----
#pragma unroll
    for (int kk = 0; kk < 2; ++kk) {
      bf16x8 af[4], bfr[4];
#pragma unroll
      for (int m = 0; m < 4; ++m) {
        int rr = wm * 64 + m * 16 + l15;
        af[m] = *(const bf16x8*)(AsB + ((rr * 128 + kk * 64 + hi * 16) ^ ((rr & 7) << 4)));
      }
#pragma unroll
      for (int n = 0; n < 4; ++n) {
        int rr = wn * 64 + n * 16 + l15;
        bfr[n] = *(const bf16x8*)(BsB + ((rr * 128 + kk * 64 + hi * 16) ^ ((rr & 7) << 4)));
      }
#pragma unroll
      for (int m = 0; m < 4; ++m)
#pragma unroll
        for (int n = 0; n < 4; ++n)
          acc[m][n] = __builtin_amdgcn_mfma_f32_16x16x32_bf16(af[m], bfr[n], acc[m][n], 0, 0, 0);
    }

    __syncthreads();  // all reads done before next iteration overwrites LDS
  }

  // ---- epilogue: y = acc + offs[o] ----
#pragma unroll
  for (int n = 0; n < 4; ++n) {
    int col = col0 + wn * 64 + n * 16 + l15;
    float off = offs[col];
#pragma unroll
    for (int m = 0; m < 4; ++m) {
      int row = row0 + wm * 64 + m * 16 + hi * 4;
      float* op = out + (size_t)row * NOUT + col;
#pragma unroll
      for (int j = 0; j < 4; ++j)
        op[(size_t)j * NOUT] = acc[m][n][j] + off;
    }
  }
}

// ---------------------------------------------------------------------------
extern "C" void kernel_launch(void* const* d_in, const int* in_sizes, int n_in,
                              void* d_out, int out_size, void* d_ws, size_t ws_size,
                              hipStream_t stream) {
  const float* x       = (const float*)d_in[0];
  const float* omega   = (const float*)d_in[1];
  const float* phase   = (const float*)d_in[2];
  const float* c_basis = (const float*)d_in[3];
  const float* bias    = (const float*)d_in[4];
  float* out = (float*)d_out;

  // ws layout: [0,2KB) offs[512] ; [2KB, 2KB+4MB) cb bf16 tiles
  float*  offs = (float*)d_ws;
  ushort* cb   = (ushort*)((char*)d_ws + 2048);

  prep_kernel<<<NOUT, 256, 0, stream>>>(omega, phase, c_basis, bias, cb, offs);
  gemm_kernel<<<(BATCH / BM) * (NOUT / BN), 256, 0, stream>>>(x, omega, phase, cb, offs, out);
}

// Round 2
// 182.688 us; speedup vs baseline: 1.1641x; 1.1641x over previous
//
#include <hip/hip_runtime.h>
#include <hip/hip_bf16.h>

// SineLayer: y[b,o] = sum_{i,d} sin(w_d*x[b,i]+p_d) * (scale_d*c[o,i,d]) + offs[o]
//   offs[o] = bias[o] + sum_{i,d} mu_d*scale_d*c[o,i,d]   (x-independent)
// GEMM: M=32768 (batch), N=512 (n_out), K=4096 (n_in*D), bf16 MFMA 16x16x32.
// R2: BM=256/BN=256 (sin redundancy 4x->2x), 8 waves, double-buffered LDS
// (128 KB dynamic), one barrier per K-step, raw v_sin (revolutions).

#define BATCH 32768
#define NIN   256
#define NOUT  512
#define DDIM  16
#define BM    256
#define BN    256
#define BK    64
#define NKT   ((NIN*DDIM)/BK)     // 64 K-steps
#define TILE_BYTES (BN*BK*2)      // 32 KB per (n_blk, kt) pre-swizzled tile
#define ABUF  32768               // bytes per A buffer (BM*BK*2)
#define EPSV  1e-8f
#define INV2PI 0.15915494309189535f

typedef short  bf16x8 __attribute__((ext_vector_type(8)));
typedef float  f32x4  __attribute__((ext_vector_type(4)));

static __device__ __forceinline__ ushort f2bf(float f) {
  union { __hip_bfloat16 h; ushort u; } cv;
  cv.h = __float2bfloat16(f);
  return cv.u;
}

// ---------------------------------------------------------------------------
// Prep: cb[o,k] = bf16(scale_d * c[o,i,d]) as pre-swizzled 256x64 tiles
// (tile idx = n_blk*NKT + kt; within tile: byte = (r*128 + kloc*2) ^ ((r&7)<<4),
// r = o&255) so a LINEAR global_load_lds copy yields the swizzled LDS image.
// Also offs[o] = bias[o] + sum mu_d*scale_d*c[o,i,d].
// ---------------------------------------------------------------------------
__global__ __launch_bounds__(256) void prep_kernel(
    const float* __restrict__ omega, const float* __restrict__ phase,
    const float* __restrict__ c_basis, const float* __restrict__ bias,
    ushort* __restrict__ cb, float* __restrict__ offs)
{
  __shared__ float s_scale[DDIM];
  __shared__ float s_musc[DDIM];
  __shared__ float s_red[4];

  const int o = blockIdx.x;
  const int t = threadIdx.x;

  if (t < DDIM) {
    float w = omega[t];
    float p = phase[t];
    float mu  = expf(-0.5f * w * w) * sinf(p);
    float var = 0.5f * (1.0f - expf(-2.0f * w * w) * cosf(2.0f * p)) - mu * mu;
    float sd  = sqrtf(fmaxf(var, 0.0f));
    float sc  = 1.0f / (sd + EPSV);
    s_scale[t] = sc;
    s_musc[t]  = mu * sc;
  }
  __syncthreads();

  const float* cp = c_basis + ((size_t)o * NIN + t) * DDIM;
  float cv[DDIM];
  {
    const float4* cp4 = (const float4*)cp;
    float4 a = cp4[0], b = cp4[1], c = cp4[2], d = cp4[3];
    cv[0]=a.x; cv[1]=a.y; cv[2]=a.z; cv[3]=a.w;
    cv[4]=b.x; cv[5]=b.y; cv[6]=b.z; cv[7]=b.w;
    cv[8]=c.x; cv[9]=c.y; cv[10]=c.z; cv[11]=c.w;
    cv[12]=d.x; cv[13]=d.y; cv[14]=d.z; cv[15]=d.w;
  }

  float partial = 0.0f;
  uint pk[8];
#pragma unroll
  for (int d = 0; d < DDIM; d += 2) {
    partial += cv[d] * s_musc[d] + cv[d+1] * s_musc[d+1];
    ushort u0 = f2bf(cv[d]   * s_scale[d]);
    ushort u1 = f2bf(cv[d+1] * s_scale[d+1]);
    pk[d >> 1] = (uint)u0 | ((uint)u1 << 16);
  }

  {
    const int r     = o & (BN - 1);
    const int n_blk = o >> 8;
    const int kt    = t >> 2;
    const int swz   = (r & 7) << 4;
    char* tile = (char*)cb + (size_t)(n_blk * NKT + kt) * TILE_BYTES;
    int b0 = r * 128 + (t & 3) * 32;
    *(uint4*)(tile + ((b0     ) ^ swz)) = make_uint4(pk[0], pk[1], pk[2], pk[3]);
    *(uint4*)(tile + ((b0 + 16) ^ swz)) = make_uint4(pk[4], pk[5], pk[6], pk[7]);
  }

#pragma unroll
  for (int off = 32; off > 0; off >>= 1) partial += __shfl_down(partial, off, 64);
  if ((t & 63) == 0) s_red[t >> 6] = partial;
  __syncthreads();
  if (t == 0) offs[o] = bias[o] + s_red[0] + s_red[1] + s_red[2] + s_red[3];
}

// ---------------------------------------------------------------------------
// Main GEMM: 256x256 tile, BK=64, 512 threads (8 waves: 4m x 2n, wave = 64x128).
// Double-buffered LDS (2x32KB A + 2x32KB B = 128 KB), single barrier per kt:
// stage(kt+1) issued before MFMA(kt) so the pre-barrier drain hides under MFMA.
// ---------------------------------------------------------------------------
__global__ __launch_bounds__(512, 2) void gemm_kernel(
    const float* __restrict__ x, const float* __restrict__ omega,
    const float* __restrict__ phase, const ushort* __restrict__ cb,
    const float* __restrict__ offs, float* __restrict__ out)
{
  extern __shared__ char lds[];   // [0,64K) = A bufs, [64K,128K) = B bufs

  const int t    = threadIdx.x;
  const int lane = t & 63;
  const int wid  = t >> 6;
  const int wm   = wid >> 1;       // 0..3
  const int wn   = wid & 1;        // 0..1
  const int bm   = blockIdx.x >> 1;
  const int bn   = blockIdx.x & 1; // bn in low bit
  const int row0 = bm * BM;
  const int col0 = bn * BN;

  // per-thread scaled omega/phase (radians -> revolutions folded in)
  float wv[DDIM], pv[DDIM];
#pragma unroll
  for (int d = 0; d < DDIM; ++d) {
    wv[d] = omega[d] * INV2PI;
    pv[d] = phase[d] * INV2PI;
  }

  f32x4 acc[4][8];
#pragma unroll
  for (int m = 0; m < 4; ++m)
#pragma unroll
    for (int n = 0; n < 8; ++n) acc[m][n] = (f32x4){0.f, 0.f, 0.f, 0.f};

  // A staging: thread -> (row r = t>>1, x-col pair (t&1)*2); 2 x -> 32 sins
  const int xr  = t >> 1;          // 0..255
  const int xc2 = (t & 1) * 2;
  const float* xbase = x + (size_t)(row0 + xr) * NIN + xc2;
  const int aswz = (xr & 7) << 4;

  const char* cbB = (const char*)cb + (size_t)bn * NKT * TILE_BYTES;

  const int hi  = lane >> 4;       // 0..3
  const int l15 = lane & 15;

#define STAGE(kt, buf)                                                         \
  {                                                                            \
    /* B: async global->LDS, linear copy of pre-swizzled 32 KB tile */         \
    const char* src = cbB + (size_t)(kt) * TILE_BYTES + wid * 4096 + lane * 16;\
    char* dst = lds + 65536 + (buf) * ABUF + wid * 4096;                       \
    __builtin_amdgcn_global_load_lds(                                          \
        (const __attribute__((address_space(1))) void*)(src),                  \
        (__attribute__((address_space(3))) void*)(dst), 16, 0, 0);             \
    __builtin_amdgcn_global_load_lds(                                          \
        (const __attribute__((address_space(1))) void*)(src + 1024),           \
        (__attribute__((address_space(3))) void*)(dst + 1024), 16, 0, 0);      \
    __builtin_amdgcn_global_load_lds(                                          \
        (const __attribute__((address_space(1))) void*)(src + 2048),           \
        (__attribute__((address_space(3))) void*)(dst + 2048), 16, 0, 0);      \
    __builtin_amdgcn_global_load_lds(                                          \
        (const __attribute__((address_space(1))) void*)(src + 3072),           \
        (__attribute__((address_space(3))) void*)(dst + 3072), 16, 0, 0);      \
    /* A: 2 x-values -> 32 sins -> bf16 -> swizzled ds_write */                \
    char* AsB = lds + (buf) * ABUF;                                            \
    float2 xv = *(const float2*)(xbase + (kt) * 4);                            \
    _Pragma("unroll")                                                          \
    for (int j = 0; j < 2; ++j) {                                              \
      float xx = j ? xv.y : xv.x;                                              \
      uint pk[8];                                                              \
      _Pragma("unroll")                                                        \
      for (int d = 0; d < DDIM; d += 2) {                                      \
        float s0 = __builtin_amdgcn_sinf(fmaf(wv[d],   xx, pv[d]));            \
        float s1 = __builtin_amdgcn_sinf(fmaf(wv[d+1], xx, pv[d+1]));          \
        pk[d >> 1] = (uint)f2bf(s0) | ((uint)f2bf(s1) << 16);                  \
      }                                                                        \
      int b0 = xr * 128 + (xc2 + j) * 32;                                      \
      *(uint4*)(AsB + ((b0     ) ^ aswz)) = make_uint4(pk[0], pk[1], pk[2], pk[3]); \
      *(uint4*)(AsB + ((b0 + 16) ^ aswz)) = make_uint4(pk[4], pk[5], pk[6], pk[7]); \
    }                                                                          \
  }

  // prologue: stage kt=0 into buf 0
  STAGE(0, 0)
  __syncthreads();

#pragma unroll 2
  for (int kt = 0; kt < NKT; ++kt) {
    const int cur = kt & 1;
    if (kt + 1 < NKT) STAGE(kt + 1, cur ^ 1)

    const char* AsB = lds + cur * ABUF;
    const char* BsB = lds + 65536 + cur * ABUF;

#pragma unroll
    for (int kk = 0; kk < 2; ++kk) {
      bf16x8 af[4], bfr[8];
#pragma unroll
      for (int m = 0; m < 4; ++m) {
        int rr = wm * 64 + m * 16 + l15;
        af[m] = *(const bf16x8*)(AsB + ((rr * 128 + kk * 64 + hi * 16) ^ ((rr & 7) << 4)));
      }
#pragma unroll
      for (int n = 0; n < 8; ++n) {
        int rr = wn * 128 + n * 16 + l15;
        bfr[n] = *(const bf16x8*)(BsB + ((rr * 128 + kk * 64 + hi * 16) ^ ((rr & 7) << 4)));
      }
#pragma unroll
      for (int m = 0; m < 4; ++m)
#pragma unroll
        for (int n = 0; n < 8; ++n)
          acc[m][n] = __builtin_amdgcn_mfma_f32_16x16x32_bf16(af[m], bfr[n], acc[m][n], 0, 0, 0);
    }

    __syncthreads();  // drains vmcnt+lgkm: buf cur^1 complete, buf cur free
  }

  // ---- epilogue: y = acc + offs[o] ----
#pragma unroll
  for (int n = 0; n < 8; ++n) {
    int col = col0 + wn * 128 + n * 16 + l15;
    float off = offs[col];
#pragma unroll
    for (int m = 0; m < 4; ++m) {
      int row = row0 + wm * 64 + m * 16 + hi * 4;
      float* op = out + (size_t)row * NOUT + col;
#pragma unroll
      for (int j = 0; j < 4; ++j)
        op[(size_t)j * NOUT] = acc[m][n][j] + off;
    }
  }
}

// ---------------------------------------------------------------------------
extern "C" void kernel_launch(void* const* d_in, const int* in_sizes, int n_in,
                              void* d_out, int out_size, void* d_ws, size_t ws_size,
                              hipStream_t stream) {
  const float* x       = (const float*)d_in[0];
  const float* omega   = (const float*)d_in[1];
  const float* phase   = (const float*)d_in[2];
  const float* c_basis = (const float*)d_in[3];
  const float* bias    = (const float*)d_in[4];
  float* out = (float*)d_out;

  // ws layout: [0,2KB) offs[512] ; [2KB, 2KB+4MB) cb bf16 tiles
  float*  offs = (float*)d_ws;
  ushort* cb   = (ushort*)((char*)d_ws + 2048);

  static int lds_attr_set = 0;
  (void)lds_attr_set;
  hipFuncSetAttribute((const void*)gemm_kernel,
                      hipFuncAttributeMaxDynamicSharedMemorySize, 131072);

  prep_kernel<<<NOUT, 256, 0, stream>>>(omega, phase, c_basis, bias, cb, offs);
  gemm_kernel<<<(BATCH / BM) * (NOUT / BN), 512, 131072, stream>>>(x, omega, phase, cb, offs, out);
}

// Round 3
// 149.426 us; speedup vs baseline: 1.4232x; 1.2226x over previous
//
#include <hip/hip_runtime.h>
#include <hip/hip_bf16.h>

// SineLayer: y[b,o] = sum_{i,d} sin(w_d*x[b,i]+p_d) * (scale_d*c[o,i,d]) + offs[o]
//   offs[o] = bias[o] + sum_{i,d} mu_d*scale_d*c[o,i,d]   (x-independent)
// GEMM: M=32768 (batch), N=512 (n_out), K=4096 (n_in*D), bf16 MFMA 16x16x32.
// R3: fixed issue order (x prefetched 1 iter ahead, AFTER B-issues) + counted
// vmcnt(1) barrier (never vmcnt(0) in loop) + setprio around MFMA cluster.

#define BATCH 32768
#define NIN   256
#define NOUT  512
#define DDIM  16
#define BM    256
#define BN    256
#define BK    64
#define NKT   ((NIN*DDIM)/BK)     // 64 K-steps
#define TILE_BYTES (BN*BK*2)      // 32 KB per (n_blk, kt) pre-swizzled tile
#define ABUF  32768               // bytes per A buffer (BM*BK*2)
#define EPSV  1e-8f
#define INV2PI 0.15915494309189535f

typedef short  bf16x8 __attribute__((ext_vector_type(8)));
typedef float  f32x4  __attribute__((ext_vector_type(4)));

static __device__ __forceinline__ ushort f2bf(float f) {
  union { __hip_bfloat16 h; ushort u; } cv;
  cv.h = __float2bfloat16(f);
  return cv.u;
}

// ---------------------------------------------------------------------------
// Prep: cb[o,k] = bf16(scale_d * c[o,i,d]) as pre-swizzled 256x64 tiles
// (tile idx = n_blk*NKT + kt; within tile: byte = (r*128 + kloc*2) ^ ((r&7)<<4),
// r = o&255) so a LINEAR global_load_lds copy yields the swizzled LDS image.
// Also offs[o] = bias[o] + sum mu_d*scale_d*c[o,i,d].
// ---------------------------------------------------------------------------
__global__ __launch_bounds__(256) void prep_kernel(
    const float* __restrict__ omega, const float* __restrict__ phase,
    const float* __restrict__ c_basis, const float* __restrict__ bias,
    ushort* __restrict__ cb, float* __restrict__ offs)
{
  __shared__ float s_scale[DDIM];
  __shared__ float s_musc[DDIM];
  __shared__ float s_red[4];

  const int o = blockIdx.x;
  const int t = threadIdx.x;

  if (t < DDIM) {
    float w = omega[t];
    float p = phase[t];
    float mu  = expf(-0.5f * w * w) * sinf(p);
    float var = 0.5f * (1.0f - expf(-2.0f * w * w) * cosf(2.0f * p)) - mu * mu;
    float sd  = sqrtf(fmaxf(var, 0.0f));
    float sc  = 1.0f / (sd + EPSV);
    s_scale[t] = sc;
    s_musc[t]  = mu * sc;
  }
  __syncthreads();

  const float* cp = c_basis + ((size_t)o * NIN + t) * DDIM;
  float cv[DDIM];
  {
    const float4* cp4 = (const float4*)cp;
    float4 a = cp4[0], b = cp4[1], c = cp4[2], d = cp4[3];
    cv[0]=a.x; cv[1]=a.y; cv[2]=a.z; cv[3]=a.w;
    cv[4]=b.x; cv[5]=b.y; cv[6]=b.z; cv[7]=b.w;
    cv[8]=c.x; cv[9]=c.y; cv[10]=c.z; cv[11]=c.w;
    cv[12]=d.x; cv[13]=d.y; cv[14]=d.z; cv[15]=d.w;
  }

  float partial = 0.0f;
  uint pk[8];
#pragma unroll
  for (int d = 0; d < DDIM; d += 2) {
    partial += cv[d] * s_musc[d] + cv[d+1] * s_musc[d+1];
    ushort u0 = f2bf(cv[d]   * s_scale[d]);
    ushort u1 = f2bf(cv[d+1] * s_scale[d+1]);
    pk[d >> 1] = (uint)u0 | ((uint)u1 << 16);
  }

  {
    const int r     = o & (BN - 1);
    const int n_blk = o >> 8;
    const int kt    = t >> 2;
    const int swz   = (r & 7) << 4;
    char* tile = (char*)cb + (size_t)(n_blk * NKT + kt) * TILE_BYTES;
    int b0 = r * 128 + (t & 3) * 32;
    *(uint4*)(tile + ((b0     ) ^ swz)) = make_uint4(pk[0], pk[1], pk[2], pk[3]);
    *(uint4*)(tile + ((b0 + 16) ^ swz)) = make_uint4(pk[4], pk[5], pk[6], pk[7]);
  }

#pragma unroll
  for (int off = 32; off > 0; off >>= 1) partial += __shfl_down(partial, off, 64);
  if ((t & 63) == 0) s_red[t >> 6] = partial;
  __syncthreads();
  if (t == 0) offs[o] = bias[o] + s_red[0] + s_red[1] + s_red[2] + s_red[3];
}

// ---------------------------------------------------------------------------
// Main GEMM: 256x256 tile, BK=64, 512 threads (8 waves: 4m x 2n, wave = 64x128).
// Double-buffered LDS (2x32KB A + 2x32KB B = 128 KB). Per iter kt:
//   [B-issue(kt+1)] [x-issue(kt+2)] [sins(x(kt+1)) -> ds_write A(kt+1)]
//   [setprio(1) MFMA(kt) setprio(0)] [vmcnt(1) lgkmcnt(0); s_barrier]
// vmcnt(1) drains B(kt+1) (which had the whole sin+MFMA phase to land) and
// keeps the x prefetch in flight. Never vmcnt(0) in the main loop.
// ---------------------------------------------------------------------------
__global__ __launch_bounds__(512, 2) void gemm_kernel(
    const float* __restrict__ x, const float* __restrict__ omega,
    const float* __restrict__ phase, const ushort* __restrict__ cb,
    const float* __restrict__ offs, float* __restrict__ out)
{
  extern __shared__ char lds[];   // [0,64K) = A bufs, [64K,128K) = B bufs

  const int t    = threadIdx.x;
  const int lane = t & 63;
  const int wid  = t >> 6;
  const int wm   = wid >> 1;       // 0..3
  const int wn   = wid & 1;        // 0..1
  const int bm   = blockIdx.x >> 1;
  const int bn   = blockIdx.x & 1;
  const int row0 = bm * BM;
  const int col0 = bn * BN;

  // per-thread scaled omega/phase (radians -> revolutions folded in)
  float wv[DDIM], pv[DDIM];
#pragma unroll
  for (int d = 0; d < DDIM; ++d) {
    wv[d] = omega[d] * INV2PI;
    pv[d] = phase[d] * INV2PI;
  }

  f32x4 acc[4][8];
#pragma unroll
  for (int m = 0; m < 4; ++m)
#pragma unroll
    for (int n = 0; n < 8; ++n) acc[m][n] = (f32x4){0.f, 0.f, 0.f, 0.f};

  // A staging: thread -> (row r = t>>1, x-col pair (t&1)*2); 2 x -> 32 sins
  const int xr  = t >> 1;          // 0..255
  const int xc2 = (t & 1) * 2;
  const float* xbase = x + (size_t)(row0 + xr) * NIN + xc2;
  const int aswz = (xr & 7) << 4;

  const char* cbB = (const char*)cb + (size_t)bn * NKT * TILE_BYTES;

  const int hi  = lane >> 4;       // 0..3
  const int l15 = lane & 15;

#define GLL(s_, d_) __builtin_amdgcn_global_load_lds(                          \
      (const __attribute__((address_space(1))) void*)(s_),                     \
      (__attribute__((address_space(3))) void*)(d_), 16, 0, 0)

  // Issue 4 global_load_lds for B-tile `kt_` into buffer `buf_`
#define ISSUE_B(kt_, buf_)                                                     \
  {                                                                            \
    const char* src = cbB + (size_t)(kt_) * TILE_BYTES + wid * 4096 + lane*16; \
    char* dst = lds + 65536 + (buf_) * ABUF + wid * 4096;                      \
    GLL(src, dst); GLL(src + 1024, dst + 1024);                                \
    GLL(src + 2048, dst + 2048); GLL(src + 3072, dst + 3072);                  \
  }

  // sins from float2 xv_ -> bf16 -> swizzled ds_write into A buffer buf_
#define STAGE_A(xv_, buf_)                                                     \
  {                                                                            \
    char* AsB = lds + (buf_) * ABUF;                                           \
    _Pragma("unroll")                                                          \
    for (int j = 0; j < 2; ++j) {                                              \
      float xx = j ? (xv_).y : (xv_).x;                                        \
      uint pk[8];                                                              \
      _Pragma("unroll")                                                        \
      for (int d = 0; d < DDIM; d += 2) {                                      \
        float s0 = __builtin_amdgcn_sinf(fmaf(wv[d],   xx, pv[d]));            \
        float s1 = __builtin_amdgcn_sinf(fmaf(wv[d+1], xx, pv[d+1]));          \
        pk[d >> 1] = (uint)f2bf(s0) | ((uint)f2bf(s1) << 16);                  \
      }                                                                        \
      int b0 = xr * 128 + (xc2 + j) * 32;                                      \
      *(uint4*)(AsB + ((b0     ) ^ aswz)) = make_uint4(pk[0],pk[1],pk[2],pk[3]); \
      *(uint4*)(AsB + ((b0 + 16) ^ aswz)) = make_uint4(pk[4],pk[5],pk[6],pk[7]); \
    }                                                                          \
  }

  // MFMA for K-step kt_ (buffers cur_ = kt_&1)
#define MFMA_STEP(cur_)                                                        \
  {                                                                            \
    const char* AsB = lds + (cur_) * ABUF;                                     \
    const char* BsB = lds + 65536 + (cur_) * ABUF;                             \
    __builtin_amdgcn_s_setprio(1);                                             \
    _Pragma("unroll")                                                          \
    for (int kk = 0; kk < 2; ++kk) {                                           \
      bf16x8 af[4], bfr[8];                                                    \
      _Pragma("unroll")                                                        \
      for (int m = 0; m < 4; ++m) {                                            \
        int rr = wm * 64 + m * 16 + l15;                                       \
        af[m] = *(const bf16x8*)(AsB + ((rr*128 + kk*64 + hi*16) ^ ((rr&7)<<4))); \
      }                                                                        \
      _Pragma("unroll")                                                        \
      for (int n = 0; n < 8; ++n) {                                            \
        int rr = wn * 128 + n * 16 + l15;                                      \
        bfr[n] = *(const bf16x8*)(BsB + ((rr*128 + kk*64 + hi*16) ^ ((rr&7)<<4))); \
      }                                                                        \
      _Pragma("unroll")                                                        \
      for (int m = 0; m < 4; ++m)                                              \
        _Pragma("unroll")                                                      \
        for (int n = 0; n < 8; ++n)                                            \
          acc[m][n] = __builtin_amdgcn_mfma_f32_16x16x32_bf16(af[m], bfr[n], acc[m][n], 0, 0, 0); \
    }                                                                          \
    __builtin_amdgcn_s_setprio(0);                                             \
  }

#define CBAR(vm_)                                                              \
  __builtin_amdgcn_sched_barrier(0);                                           \
  asm volatile("s_waitcnt vmcnt(" #vm_ ") lgkmcnt(0)" ::: "memory");           \
  __builtin_amdgcn_s_barrier();                                                \
  __builtin_amdgcn_sched_barrier(0);

  // One loop iteration: use x slot XU_ (slice kt_+1), load x slot XL_ (slice kt_+2)
#define BODY(kt_, XU_, XL_)                                                    \
  {                                                                            \
    ISSUE_B(((kt_) + 1 < NKT ? (kt_) + 1 : NKT - 1), ((kt_) + 1) & 1);         \
    __builtin_amdgcn_sched_barrier(0);                                         \
    XL_ = *(const float2*)(xbase + ((kt_) + 2 < NKT ? (kt_) + 2 : NKT - 1)*4); \
    __builtin_amdgcn_sched_barrier(0);                                         \
    STAGE_A(XU_, ((kt_) + 1) & 1);                                             \
    MFMA_STEP((kt_) & 1);                                                      \
    CBAR(1)                                                                    \
  }

  // ---- prologue: x(0), B(0), x(1); stage A(0); barrier keeping x(1) ----
  float2 xs0, xs1;
  {
    float2 xp = *(const float2*)(xbase);          // x slice 0 (oldest)
    __builtin_amdgcn_sched_barrier(0);
    ISSUE_B(0, 0);
    __builtin_amdgcn_sched_barrier(0);
    xs1 = *(const float2*)(xbase + 4);            // x slice 1 (newest)
    __builtin_amdgcn_sched_barrier(0);
    STAGE_A(xp, 0);
    CBAR(1)                                       // drains B(0), keeps xs1
  }

  for (int kt = 0; kt < NKT; kt += 2) {
    BODY(kt,     xs1, xs0)
    BODY(kt + 1, xs0, xs1)
  }

  // ---- epilogue: y = acc + offs[o] ----
#pragma unroll
  for (int n = 0; n < 8; ++n) {
    int col = col0 + wn * 128 + n * 16 + l15;
    float off = offs[col];
#pragma unroll
    for (int m = 0; m < 4; ++m) {
      int row = row0 + wm * 64 + m * 16 + hi * 4;
      float* op = out + (size_t)row * NOUT + col;
#pragma unroll
      for (int j = 0; j < 4; ++j)
        op[(size_t)j * NOUT] = acc[m][n][j] + off;
    }
  }
}

// ---------------------------------------------------------------------------
extern "C" void kernel_launch(void* const* d_in, const int* in_sizes, int n_in,
                              void* d_out, int out_size, void* d_ws, size_t ws_size,
                              hipStream_t stream) {
  const float* x       = (const float*)d_in[0];
  const float* omega   = (const float*)d_in[1];
  const float* phase   = (const float*)d_in[2];
  const float* c_basis = (const float*)d_in[3];
  const float* bias    = (const float*)d_in[4];
  float* out = (float*)d_out;

  // ws layout: [0,2KB) offs[512] ; [2KB, 2KB+4MB) cb bf16 tiles
  float*  offs = (float*)d_ws;
  ushort* cb   = (ushort*)((char*)d_ws + 2048);

  hipFuncSetAttribute((const void*)gemm_kernel,
                      hipFuncAttributeMaxDynamicSharedMemorySize, 131072);

  prep_kernel<<<NOUT, 256, 0, stream>>>(omega, phase, c_basis, bias, cb, offs);
  gemm_kernel<<<(BATCH / BM) * (NOUT / BN), 512, 131072, stream>>>(x, omega, phase, cb, offs, out);
}